// Round 6
// baseline (209.509 us; speedup 1.0000x reference)
//
#include <hip/hip_runtime.h>
#include <stdint.h>

typedef unsigned short u16;
typedef __attribute__((ext_vector_type(8))) short short8;
typedef __attribute__((ext_vector_type(4))) float f32x4;

#define NTRACE 4096
#define TLEN   64
#define ISZ    64
#define HSZ    128
#define NBLK   NTRACE            // 1 trace per 128-thread block (2 waves)

__device__ __forceinline__ float bf2f(u16 u) {
  union { uint32_t i; float f; } v; v.i = ((uint32_t)u) << 16; return v.f;
}
__device__ __forceinline__ u16 f2bf(float f) {
  union { float f; uint32_t i; } v; v.f = f;
  uint32_t r = v.i + 0x7fffu + ((v.i >> 16) & 1u);
  return (u16)(r >> 16);
}
// tanh(gc)*sigm(go) with 2 exp + 1 rcp (exact rewrite)
__device__ __forceinline__ float gate_pair(float go, float gc) {
  float E = __expf(2.0f * gc);
  float B = __expf(-go);
  return (E - 1.0f) * __builtin_amdgcn_rcpf((E + 1.0f) * (1.0f + B));
}

// ---------------------------------------------------------------------------
// k_prep: one-time f32->bf16 conversion (weights + embedding table), bias
// sums, and zeroing of the reduce counter. Grid: 2500x256 = 640000 threads.
// ---------------------------------------------------------------------------
__global__ __launch_bounds__(256) void k_prep(
    const float* __restrict__ emb,
    const float* __restrict__ W1, const float* __restrict__ W2,
    const float* __restrict__ Wp1,
    const float* __restrict__ b_ih1, const float* __restrict__ b_hh1,
    const float* __restrict__ b_ih2, const float* __restrict__ b_hh2,
    u16* __restrict__ embb,
    u16* __restrict__ w1b, u16* __restrict__ w2b, u16* __restrict__ wp1b,
    float* __restrict__ bs1, float* __restrict__ bs2,
    unsigned int* __restrict__ counter)
{
  const int i = blockIdx.x * 256 + threadIdx.x;
  if (i < 10000 * 64) embb[i] = f2bf(emb[i]);
  if (i < 512 * 64)   w1b[i]  = f2bf(W1[i]);
  if (i < 512 * 128)  w2b[i]  = f2bf(W2[i]);
  if (i < 64 * 128)   wp1b[i] = f2bf(Wp1[i]);
  if (i < 512) { bs1[i] = b_ih1[i] + b_hh1[i]; bs2[i] = b_ih2[i] + b_hh2[i]; }
  if (i == 0) *counter = 0u;
}

// ---------------------------------------------------------------------------
// trace_body<NG>: one trace per 2-wave block; wave w handles mt tiles
// {4w..4w+3} of both LSTM layers (m = h dimension). Energy/softmax computed
// redundantly by both waves (cheap); weighted sum split by position.
// hbuf XOR-chunk swizzle: (token,h) -> column ((h>>3)^(token&15))*8 + (h&7).
// ---------------------------------------------------------------------------
template<int NG>
__device__ __forceinline__ void trace_body(
    u16* __restrict__ hbuf,            // [TLEN][HSZ] flat
    float* __restrict__ wbuf,          // [TLEN] softmax weights
    const u16* __restrict__ embb,
    const u16* __restrict__ w1b, const float* __restrict__ bs1,
    const u16* __restrict__ w2b, const float* __restrict__ bs2,
    const u16* __restrict__ wp1b,
    const float* __restrict__ bp1v, const float* __restrict__ Wp2,
    const float* __restrict__ bp2v,
    const int* __restrict__ traces,
    float* __restrict__ partials, int t, int len)
{
  const int lane = threadIdx.x & 63;
  const int w    = threadIdx.x >> 6;     // wave id 0/1
  const int col  = lane & 15;
  const int q    = lane >> 4;
  const f32x4 z = {0.f, 0.f, 0.f, 0.f};

  // ---- x fragments (B-operand of lstm1), bf16 gather
  short8 xf[NG][2];
#pragma unroll
  for (int g = 0; g < NG; ++g) {
    const int tok = traces[t * TLEN + g * 16 + col];
    const u16* xr = embb + (size_t)tok * ISZ + q * 8;
    xf[g][0] = *(const short8*)(xr);
    xf[g][1] = *(const short8*)(xr + 32);
  }

  // ---- LSTM layer 1 (K=64); wave handles mt = 4w..4w+3
#pragma unroll
  for (int mtl = 0; mtl < 4; ++mtl) {
    const int mt = 4 * w + mtl;
    f32x4 aI[NG], aC[NG], aO[NG];
#pragma unroll
    for (int g = 0; g < NG; ++g) { aI[g] = z; aC[g] = z; aO[g] = z; }
#pragma unroll
    for (int ks = 0; ks < 2; ++ks) {
      const u16* wb = w1b + ks * 32 + q * 8;
      short8 fI = *(const short8*)(wb + (size_t)(mt * 16 + col) * ISZ);
      short8 fC = *(const short8*)(wb + (size_t)(256 + mt * 16 + col) * ISZ);
      short8 fO = *(const short8*)(wb + (size_t)(384 + mt * 16 + col) * ISZ);
#pragma unroll
      for (int g = 0; g < NG; ++g) {
        aI[g] = __builtin_amdgcn_mfma_f32_16x16x32_bf16(fI, xf[g][ks], aI[g], 0, 0, 0);
        aC[g] = __builtin_amdgcn_mfma_f32_16x16x32_bf16(fC, xf[g][ks], aC[g], 0, 0, 0);
        aO[g] = __builtin_amdgcn_mfma_f32_16x16x32_bf16(fO, xf[g][ks], aO[g], 0, 0, 0);
      }
    }
    float bI[4], bC[4], bO[4];
#pragma unroll
    for (int r = 0; r < 4; ++r) {
      const int h = mt * 16 + q * 4 + r;
      bI[r] = bs1[h]; bC[r] = bs1[256 + h]; bO[r] = bs1[384 + h];
    }
    const int wcol = ((mt * 2 + (q >> 1)) ^ col) * 8 + (q & 1) * 4;
#pragma unroll
    for (int g = 0; g < NG; ++g) {
      u16 hv[4];
#pragma unroll
      for (int r = 0; r < 4; ++r) {
        float c = gate_pair(aI[g][r] + bI[r], aC[g][r] + bC[r]);
        hv[r] = f2bf(gate_pair(aO[g][r] + bO[r], c));
      }
      uint2 pk;
      pk.x = (uint32_t)hv[0] | ((uint32_t)hv[1] << 16);
      pk.y = (uint32_t)hv[2] | ((uint32_t)hv[3] << 16);
      *(uint2*)&hbuf[(g * 16 + col) * HSZ + wcol] = pk;
    }
  }
  __syncthreads();   // both waves' h1 halves visible

  // ---- h1 fragments (B-operand of lstm2, full K), swizzled reads
  short8 hf[NG][4];
#pragma unroll
  for (int g = 0; g < NG; ++g)
#pragma unroll
    for (int ks = 0; ks < 4; ++ks)
      hf[g][ks] = *(const short8*)&hbuf[(g * 16 + col) * HSZ + ((ks * 4 + q) ^ col) * 8];
  __syncthreads();   // reads done before overwrite

  // ---- LSTM layer 2 (K=128); wave handles mt = 4w..4w+3
#pragma unroll
  for (int mtl = 0; mtl < 4; ++mtl) {
    const int mt = 4 * w + mtl;
    f32x4 aI[NG], aC[NG], aO[NG];
#pragma unroll
    for (int g = 0; g < NG; ++g) { aI[g] = z; aC[g] = z; aO[g] = z; }
#pragma unroll
    for (int ks = 0; ks < 4; ++ks) {
      const u16* wb = w2b + ks * 32 + q * 8;
      short8 fI = *(const short8*)(wb + (size_t)(mt * 16 + col) * HSZ);
      short8 fC = *(const short8*)(wb + (size_t)(256 + mt * 16 + col) * HSZ);
      short8 fO = *(const short8*)(wb + (size_t)(384 + mt * 16 + col) * HSZ);
#pragma unroll
      for (int g = 0; g < NG; ++g) {
        aI[g] = __builtin_amdgcn_mfma_f32_16x16x32_bf16(fI, hf[g][ks], aI[g], 0, 0, 0);
        aC[g] = __builtin_amdgcn_mfma_f32_16x16x32_bf16(fC, hf[g][ks], aC[g], 0, 0, 0);
        aO[g] = __builtin_amdgcn_mfma_f32_16x16x32_bf16(fO, hf[g][ks], aO[g], 0, 0, 0);
      }
    }
    float bI[4], bC[4], bO[4];
#pragma unroll
    for (int r = 0; r < 4; ++r) {
      const int h = mt * 16 + q * 4 + r;
      bI[r] = bs2[h]; bC[r] = bs2[256 + h]; bO[r] = bs2[384 + h];
    }
    const int wcol = ((mt * 2 + (q >> 1)) ^ col) * 8 + (q & 1) * 4;
#pragma unroll
    for (int g = 0; g < NG; ++g) {
      u16 hv[4];
#pragma unroll
      for (int r = 0; r < 4; ++r) {
        float c = gate_pair(aI[g][r] + bI[r], aC[g][r] + bC[r]);
        hv[r] = f2bf(gate_pair(aO[g][r] + bO[r], c));
      }
      uint2 pk;
      pk.x = (uint32_t)hv[0] | ((uint32_t)hv[1] << 16);
      pk.y = (uint32_t)hv[2] | ((uint32_t)hv[3] << 16);
      *(uint2*)&hbuf[(g * 16 + col) * HSZ + wcol] = pk;
    }
  }
  __syncthreads();

  // ---- reload fragments: now h2 (both waves, full)
#pragma unroll
  for (int g = 0; g < NG; ++g)
#pragma unroll
    for (int ks = 0; ks < 4; ++ks)
      hf[g][ks] = *(const short8*)&hbuf[(g * 16 + col) * HSZ + ((ks * 4 + q) ^ col) * 8];

  // ---- attention-MLP energy (redundant in both waves; both hold full hf)
  float ep[NG];
#pragma unroll
  for (int g = 0; g < NG; ++g) ep[g] = 0.f;
#pragma unroll
  for (int mt = 0; mt < 4; ++mt) {
    f32x4 acc[NG];
#pragma unroll
    for (int g = 0; g < NG; ++g) acc[g] = z;
#pragma unroll
    for (int ks = 0; ks < 4; ++ks) {
      short8 fA = *(const short8*)(wp1b + (size_t)(mt * 16 + col) * HSZ + ks * 32 + q * 8);
#pragma unroll
      for (int g = 0; g < NG; ++g)
        acc[g] = __builtin_amdgcn_mfma_f32_16x16x32_bf16(fA, hf[g][ks], acc[g], 0, 0, 0);
    }
#pragma unroll
    for (int r = 0; r < 4; ++r) {
      const int hp = mt * 16 + q * 4 + r;
      const float b1 = bp1v[hp];
      const float w2 = Wp2[hp];
#pragma unroll
      for (int g = 0; g < NG; ++g)
        ep[g] += fmaxf(acc[g][r] + b1, 0.f) * w2;
    }
  }
#pragma unroll
  for (int g = 0; g < NG; ++g) {
    ep[g] += __shfl_xor(ep[g], 16);
    ep[g] += __shfl_xor(ep[g], 32);
  }
  const float bp2f = bp2v[0];

  // ---- masked softmax (token l = g*16 + col), redundant in both waves
  float e[NG]; bool val[NG];
  float m = -3.0e38f;
#pragma unroll
  for (int g = 0; g < NG; ++g) {
    val[g] = (g * 16 + col) < len;
    e[g] = ep[g] + bp2f;
    m = fmaxf(m, val[g] ? e[g] : -3.0e38f);
  }
  m = fmaxf(m, __shfl_xor(m, 1));
  m = fmaxf(m, __shfl_xor(m, 2));
  m = fmaxf(m, __shfl_xor(m, 4));
  m = fmaxf(m, __shfl_xor(m, 8));
  float wgt[NG], s = 0.f;
#pragma unroll
  for (int g = 0; g < NG; ++g) {
    wgt[g] = val[g] ? __expf(e[g] - m) : 0.f;
    s += wgt[g];
  }
  s += __shfl_xor(s, 1);
  s += __shfl_xor(s, 2);
  s += __shfl_xor(s, 4);
  s += __shfl_xor(s, 8);
  const float inv = __builtin_amdgcn_rcpf(s);
  if (w == 0 && q == 0) {
#pragma unroll
    for (int g = 0; g < NG; ++g) wbuf[g * 16 + col] = wgt[g] * inv;
  }
  __syncthreads();

  // ---- weighted sum: te[h] = sum_l w[l]*h2[l][h]; wave w takes positions
  // l = g*16 + 2*(4w+ii) + half, ii=0..3; lane covers h = 4*(lane&31)..+3
  const int half = lane >> 5;
  const int hb   = (lane & 31) * 4;
  const int rchunk = hb >> 3;
  float a4[4] = {0.f, 0.f, 0.f, 0.f};
#pragma unroll
  for (int g = 0; g < NG; ++g) {
#pragma unroll
    for (int ii = 0; ii < 4; ++ii) {
      const int l = g * 16 + 2 * (4 * w + ii) + half;
      const float wl = wbuf[l];
      const int sw = ((rchunk ^ (l & 15)) * 8) + (hb & 7);
      const uint2 hv = *(const uint2*)&hbuf[l * HSZ + sw];
      a4[0] += wl * bf2f((u16)(hv.x & 0xffffu));
      a4[1] += wl * bf2f((u16)(hv.x >> 16));
      a4[2] += wl * bf2f((u16)(hv.y & 0xffffu));
      a4[3] += wl * bf2f((u16)(hv.y >> 16));
    }
  }
#pragma unroll
  for (int k = 0; k < 4; ++k) a4[k] += __shfl_xor(a4[k], 32);

  __syncthreads();                    // all reads of hbuf complete
  float* teb = (float*)hbuf;          // overlay: 2 waves x 128 floats = 1 KB
  if (half == 0) {
    f32x4 st = {a4[0], a4[1], a4[2], a4[3]};
    *(f32x4*)&teb[w * HSZ + hb] = st;
  }
  __syncthreads();

  if (threadIdx.x < HSZ)
    partials[(size_t)t * HSZ + threadIdx.x] =
        teb[threadIdx.x] + teb[HSZ + threadIdx.x];
}

// ---------------------------------------------------------------------------
// k_fused: 1 trace per 128-thread (2-wave) block; uniform template dispatch.
// ---------------------------------------------------------------------------
__global__ __launch_bounds__(128) void k_fused(
    const u16* __restrict__ embb,
    const u16* __restrict__ w1b, const float* __restrict__ bs1,
    const u16* __restrict__ w2b, const float* __restrict__ bs2,
    const u16* __restrict__ wp1b,
    const float* __restrict__ bp1v, const float* __restrict__ Wp2,
    const float* __restrict__ bp2v,
    const int* __restrict__ traces, const int* __restrict__ lengths,
    float* __restrict__ partials)
{
  __shared__ u16 hbuf[TLEN * HSZ];   // 16 KB
  __shared__ float wbuf[TLEN];       // 256 B
  const int t = blockIdx.x;
  const int len = lengths[t];
  const int ngrp = (len + 15) >> 4;
  switch (ngrp) {
    case 1: trace_body<1>(hbuf, wbuf, embb, w1b, bs1, w2b, bs2, wp1b,
                          bp1v, Wp2, bp2v, traces, partials, t, len); break;
    case 2: trace_body<2>(hbuf, wbuf, embb, w1b, bs1, w2b, bs2, wp1b,
                          bp1v, Wp2, bp2v, traces, partials, t, len); break;
    case 3: trace_body<3>(hbuf, wbuf, embb, w1b, bs1, w2b, bs2, wp1b,
                          bp1v, Wp2, bp2v, traces, partials, t, len); break;
    default: trace_body<4>(hbuf, wbuf, embb, w1b, bs1, w2b, bs2, wp1b,
                           bp1v, Wp2, bp2v, traces, partials, t, len); break;
  }
}

// ---------------------------------------------------------------------------
// k_reduce: block h sums partials[:,h] -> fin[h]; the LAST finishing block
// (device-scope counter) additionally computes out = fin @ W_out.T + b_out.
// ---------------------------------------------------------------------------
__global__ __launch_bounds__(256) void k_reduce(
    const float* __restrict__ partials, float* __restrict__ fin,
    unsigned int* __restrict__ counter,
    const float* __restrict__ W_out, const float* __restrict__ b_out,
    float* __restrict__ out)
{
  const int h = blockIdx.x;
  const int tid = threadIdx.x;
  float s = 0.f;
  for (int b = tid; b < NTRACE; b += 256) s += partials[(size_t)b * HSZ + h];
#pragma unroll
  for (int off = 32; off >= 1; off >>= 1) s += __shfl_xor(s, off);
  __shared__ float part[4];
  __shared__ bool last;
  if ((tid & 63) == 0) part[tid >> 6] = s;
  __syncthreads();
  if (tid == 0) {
    fin[h] = part[0] + part[1] + part[2] + part[3];
    __threadfence();
    last = (atomicAdd(counter, 1u) == (unsigned)(HSZ - 1));
  }
  __syncthreads();
  if (last && tid < HSZ) {
    __threadfence();
    const int o = tid;
    float acc = b_out[o];
    const float* wr = W_out + (size_t)o * HSZ;
#pragma unroll
    for (int k = 0; k < HSZ; ++k) acc += wr[k] * fin[k];
    out[o] = acc;
  }
}

extern "C" void kernel_launch(void* const* d_in, const int* in_sizes, int n_in,
                              void* d_out, int out_size, void* d_ws, size_t ws_size,
                              hipStream_t stream)
{
  const float* emb   = (const float*)d_in[0];
  const float* W_ih1 = (const float*)d_in[1];
  // d_in[2] = W_hh1: unused (h0 = 0)
  const float* b_ih1 = (const float*)d_in[3];
  const float* b_hh1 = (const float*)d_in[4];
  const float* W_ih2 = (const float*)d_in[5];
  // d_in[6] = W_hh2: unused
  const float* b_ih2 = (const float*)d_in[7];
  const float* b_hh2 = (const float*)d_in[8];
  const float* Wp1   = (const float*)d_in[9];
  const float* bp1   = (const float*)d_in[10];
  const float* Wp2   = (const float*)d_in[11];
  const float* bp2   = (const float*)d_in[12];
  const float* W_out = (const float*)d_in[13];
  const float* b_out = (const float*)d_in[14];
  const int* traces  = (const int*)d_in[15];
  const int* lengths = (const int*)d_in[16];

  char* ws = (char*)d_ws;
  u16*   w1b      = (u16*)(ws);                   // 65536 B
  u16*   w2b      = (u16*)(ws + 65536);           // 131072 B
  u16*   wp1b     = (u16*)(ws + 196608);          // 16384 B
  float* bs1      = (float*)(ws + 212992);        // 2048 B
  float* bs2      = (float*)(ws + 215040);        // 2048 B
  float* fin      = (float*)(ws + 217088);        // 512 B
  unsigned int* counter = (unsigned int*)(ws + 217600);  // 512 B (4 used)
  u16*   embb     = (u16*)(ws + 218112);          // 10000*64*2 = 1280000 B
  float* partials = (float*)(ws + 1499136);       // 4096*128*4 = 2 MiB -> ends ~3.6 MB

  k_prep<<<2500, 256, 0, stream>>>(emb, W_ih1, W_ih2, Wp1,
                                   b_ih1, b_hh1, b_ih2, b_hh2,
                                   embb, w1b, w2b, wp1b, bs1, bs2, counter);
  k_fused<<<NBLK, 128, 0, stream>>>(embb, w1b, bs1, w2b, bs2, wp1b,
                                    bp1, Wp2, bp2, traces, lengths, partials);
  k_reduce<<<HSZ, 256, 0, stream>>>(partials, fin, counter, W_out, b_out,
                                    (float*)d_out);
}